// Round 6
// baseline (501.216 us; speedup 1.0000x reference)
//
#include <hip/hip_runtime.h>
#include <hip/hip_bf16.h>
#include <math.h>

// Problem constants (fixed by setup_inputs)
#define B  4
#define P  5000
#define NPT 100
#define F  64          // pointnet feature dim
#define NX 240
#define NY 240
#define C1 128         // conv1/conv2 out channels
#define YP 248         // padded y-stride (rows yi = gy+1; halos zeroed)

typedef __attribute__((ext_vector_type(8)))  short short8;   // 8 bf16
typedef __attribute__((ext_vector_type(16))) float f32x16;

// tanh via v_exp + v_rcp (rel err ~1e-6; saturates correctly at +-1)
__device__ __forceinline__ float tanh_fast(float x) {
    float e = exp2f(x * 2.8853900817779268f);   // 2*log2(e): single v_exp
    float r = __builtin_amdgcn_rcpf(e + 1.0f);
    return __builtin_fmaf(-2.0f, r, 1.0f);
}
__device__ __forceinline__ short bf16_bits(float f) {
    return (short)(__bfloat16_as_ushort(__float2bfloat16(f)));
}

// ---------------------------------------------------------------------------
// PointNet, both layers on MFMA — R17 register-resident handoff (unchanged,
// except img writes go to the y-padded layout).
// ---------------------------------------------------------------------------
__global__ __launch_bounds__(128, 2) void pn_mfma_kernel(
    const float* __restrict__ pillars,    // [B,P,N,8]
    const short* __restrict__ w0p,        // [4 slots][64 feat][8 j] bf16 bits
    const __hip_bfloat16* __restrict__ w1t, // [64 n][64 k-permuted] bf16
    const float* __restrict__ b1,         // [64]
    const int* __restrict__ idxs,         // [B*P][2]
    const int* __restrict__ winner,       // [B*NX*NY]
    __hip_bfloat16* __restrict__ img)     // [B][NX][YP][F] padded
{
    constexpr int XS = 40;                // 80B row: bank stride 20 -> max 4-way
    __shared__ short xA[128 * XS];        // 10,240 B
    __shared__ float red[2][F];
    __shared__ unsigned int vb32[4];

    int bp = blockIdx.x;
    int n  = threadIdx.x;
    int wave = n >> 6, lane = n & 63;
    int mr = lane & 31;
    int g  = lane >> 5;
    bool live = (n < NPT);

    const float* xp = pillars + ((size_t)bp * NPT + (live ? n : 0)) * 8;
    float4 q0 = *(const float4*)xp;
    float4 q1 = *(const float4*)(xp + 4);
    float x[8] = {q0.x, q0.y, q0.z, q0.w, q1.x, q1.y, q1.z, q1.w};

    float ss = 0.f;
#pragma unroll
    for (int c = 0; c < 8; c++) ss += x[c] * x[c];
    bool valid = live && (ss < 1e12f);

    unsigned long long bal = __ballot(valid);
    if (lane == 0) {
        vb32[wave * 2]     = (unsigned)bal;
        vb32[wave * 2 + 1] = (unsigned)(bal >> 32);
    }

    short8 xhi, xlo, xone;
#pragma unroll
    for (int c = 0; c < 8; c++) {
        __hip_bfloat16 hb = __float2bfloat16(x[c]);
        float hv = __bfloat162float(hb);
        xhi[c] = (short)__bfloat16_as_ushort(hb);
        xlo[c] = bf16_bits(x[c] - hv);
        xone[c] = (c < 2) ? bf16_bits(1.0f) : (short)0;   // one-hot for bias hi+lo
    }
    *(short8*)&xA[n * XS + 0]  = xhi;
    *(short8*)&xA[n * XS + 8]  = xlo;
    *(short8*)&xA[n * XS + 16] = xhi;
    *(short8*)&xA[n * XS + 24] = xone;
    __syncthreads();

    short8 wb[2][2];
#pragma unroll
    for (int kk = 0; kk < 2; kk++)
#pragma unroll
        for (int m = 0; m < 2; m++)
            wb[kk][m] = *(const short8*)(w0p + ((kk * 2 + g) * 64 + m * 32 + mr) * 8);

    f32x16 acc1[2][2];
#pragma unroll
    for (int ptt = 0; ptt < 2; ptt++)
#pragma unroll
        for (int m = 0; m < 2; m++)
            acc1[ptt][m] = (f32x16){0,0,0,0,0,0,0,0,0,0,0,0,0,0,0,0};

#pragma unroll
    for (int kk = 0; kk < 2; kk++) {
        short8 x0 = *(const short8*)&xA[(wave * 64 + mr) * XS + kk * 16 + g * 8];
        short8 x1 = *(const short8*)&xA[(wave * 64 + 32 + mr) * XS + kk * 16 + g * 8];
        acc1[0][0] = __builtin_amdgcn_mfma_f32_32x32x16_bf16(wb[kk][0], x0, acc1[0][0], 0, 0, 0);
        acc1[0][1] = __builtin_amdgcn_mfma_f32_32x32x16_bf16(wb[kk][1], x0, acc1[0][1], 0, 0, 0);
        acc1[1][0] = __builtin_amdgcn_mfma_f32_32x32x16_bf16(wb[kk][0], x1, acc1[1][0], 0, 0, 0);
        acc1[1][1] = __builtin_amdgcn_mfma_f32_32x32x16_bf16(wb[kk][1], x1, acc1[1][1], 0, 0, 0);
    }

    short8 afrag[2][4];
#pragma unroll
    for (int ptt = 0; ptt < 2; ptt++) {
#pragma unroll
        for (int c0 = 0; c0 < 4; c0++) {
            short8 t;
#pragma unroll
            for (int j = 0; j < 8; j++) {
                float v = (c0 >> 1) ? acc1[ptt][1][8 * (c0 & 1) + j]
                                    : acc1[ptt][0][8 * (c0 & 1) + j];
                t[j] = bf16_bits(tanh_fast(v));
            }
            afrag[ptt][c0] = t;
        }
    }

    short8 bfrag[2][4];
#pragma unroll
    for (int nt = 0; nt < 2; nt++)
#pragma unroll
        for (int c0 = 0; c0 < 4; c0++)
            bfrag[nt][c0] = *(const short8*)((const short*)w1t +
                                (nt * 32 + mr) * F + c0 * 16 + g * 8);

    f32x16 a2[2][2];
#pragma unroll
    for (int ptt = 0; ptt < 2; ptt++)
#pragma unroll
        for (int nt = 0; nt < 2; nt++)
            a2[ptt][nt] = (f32x16){0,0,0,0,0,0,0,0,0,0,0,0,0,0,0,0};

#pragma unroll
    for (int c0 = 0; c0 < 4; c0++) {
        a2[0][0] = __builtin_amdgcn_mfma_f32_32x32x16_bf16(afrag[0][c0], bfrag[0][c0], a2[0][0], 0, 0, 0);
        a2[0][1] = __builtin_amdgcn_mfma_f32_32x32x16_bf16(afrag[0][c0], bfrag[1][c0], a2[0][1], 0, 0, 0);
        a2[1][0] = __builtin_amdgcn_mfma_f32_32x32x16_bf16(afrag[1][c0], bfrag[0][c0], a2[1][0], 0, 0, 0);
        a2[1][1] = __builtin_amdgcn_mfma_f32_32x32x16_bf16(afrag[1][c0], bfrag[1][c0], a2[1][1], 0, 0, 0);
    }

    float bv0 = b1[mr];
    float bv1 = b1[32 + mr];
    bool allv = ((vb32[0] & vb32[1] & vb32[2]) == 0xFFFFFFFFu) &&
                ((vb32[3] & 0xFu) == 0xFu);
    float mx0 = -INFINITY, mx1 = -INFINITY;

    if (allv) {
#pragma unroll
        for (int ptt = 0; ptt < 2; ptt++) {
#pragma unroll
            for (int r = 0; r < 16; r++) {
                bool inc = !(wave == 1 && ptt == 1) || (g == 0 && r < 4);
                if (inc) {
                    mx0 = fmaxf(mx0, (ptt == 0) ? a2[0][0][r] : a2[1][0][r]);
                    mx1 = fmaxf(mx1, (ptt == 0) ? a2[0][1][r] : a2[1][1][r]);
                }
            }
        }
        mx0 += bv0;
        mx1 += bv1;
    } else {
        unsigned wm0 = vb32[wave * 2];
        unsigned wm1 = vb32[wave * 2 + 1];
#pragma unroll
        for (int ptt = 0; ptt < 2; ptt++) {
            unsigned wm = (ptt == 0) ? wm0 : wm1;
#pragma unroll
            for (int r = 0; r < 16; r++) {
                int idx = (r & 3) + 8 * (r >> 2) + 4 * g;
                bool inc = !(wave == 1 && ptt == 1) || (idx < 4);
                if (inc) {
                    bool vbit = (wm >> idx) & 1;
                    float a0 = (ptt == 0) ? a2[0][0][r] : a2[1][0][r];
                    float a1 = (ptt == 0) ? a2[0][1][r] : a2[1][1][r];
                    mx0 = fmaxf(mx0, vbit ? (a0 + bv0) : 0.0f);
                    mx1 = fmaxf(mx1, vbit ? (a1 + bv1) : 0.0f);
                }
            }
        }
    }
    mx0 = fmaxf(mx0, __shfl_xor(mx0, 32, 64));
    mx1 = fmaxf(mx1, __shfl_xor(mx1, 32, 64));
    if (lane < 32) { red[wave][mr] = mx0; red[wave][32 + mr] = mx1; }
    __syncthreads();
    if (n < F) {
        float v = fmaxf(red[0][n], red[1][n]);
        int ix = idxs[bp * 2], iy = idxs[bp * 2 + 1];
        int b = bp / P, p = bp % P;
        if (winner[(b * NX + ix) * NY + iy] == p)
            img[((size_t)(b * NX + ix) * YP + iy + 1) * F + n] = __float2bfloat16(v);
    }
}

// ---------------------------------------------------------------------------
// Scatter winner: numpy last-write-wins via atomicMax(p). Runs BEFORE pn.
// ---------------------------------------------------------------------------
__global__ __launch_bounds__(256) void winner_kernel(
    const int* __restrict__ idxs, int* __restrict__ winner)
{
    int i = blockIdx.x * 256 + threadIdx.x;
    if (i >= B * P) return;
    int ix = idxs[i * 2], iy = idxs[i * 2 + 1];
    int b = i / P, p = i % P;
    atomicMax(&winner[(b * NX + ix) * NY + iy], p);
}

// Zero the y-halo rows of out1 (yi in {0,241,242,243}); real rows 1..240 are
// fully written by conv1, so no full-buffer memset needed.
__global__ __launch_bounds__(256) void halo_kernel(__hip_bfloat16* __restrict__ out1)
{
    int idx = blockIdx.x * 256 + threadIdx.x;
    if (idx >= B * NX * 4 * (C1 / 8)) return;   // 61,440 short8 stores
    int c8   = idx & 15;          // 16 x short8 per row
    int rest = idx >> 4;
    int rowi = rest & 3;
    int rest2 = rest >> 2;
    int x = rest2 % NX, b = rest2 / NX;
    int yi = (rowi == 0) ? 0 : (240 + rowi);    // 0,241,242,243
    short8 z = {0,0,0,0,0,0,0,0};
    *(short8*)&out1[(((size_t)(b * NX + x)) * YP + yi) * C1 + c8 * 8] = z;
}

// ---------------------------------------------------------------------------
// Weight converts. Conv weights -> [tap][ci/16][128 co][16 ci] bf16.
// ---------------------------------------------------------------------------
__global__ __launch_bounds__(256) void cvt_w_kernel(
    const float* __restrict__ w, __hip_bfloat16* __restrict__ wt, int cin)
{
    int idx = blockIdx.x * 256 + threadIdx.x;
    int total = 9 * cin * 128;
    if (idx >= total) return;
    int co = idx % 128;
    int rest = idx / 128;
    int ci = rest % cin;
    int t  = rest / cin;
    int c0 = ci >> 4, c16 = ci & 15;
    wt[(((size_t)(t * (cin >> 4) + c0)) * 128 + co) * 16 + c16] = __float2bfloat16(w[idx]);
}

// w1 [64 k][64 n] fp32 -> w1t [n][kk'] bf16 with k-permutation
__global__ __launch_bounds__(256) void cvt_w1_kernel(
    const float* __restrict__ w1, __hip_bfloat16* __restrict__ w1t)
{
    int idx = blockIdx.x * 256 + threadIdx.x;
    if (idx >= F * F) return;
    int nn = idx >> 6, kk = idx & 63;
    int c0 = kk >> 4, g = (kk >> 3) & 1, j = kk & 7;
    int k = 16 * c0 + 4 * g + (j & 3) + 8 * (j >> 2);
    w1t[nn * F + kk] = __float2bfloat16(w1[k * F + nn]);
}

// w0 [8,64] fp32 + b0 [64] -> w0p [4 slots][64 feat][8 j] bf16 bits.
__global__ __launch_bounds__(256) void cvt_w0p_kernel(
    const float* __restrict__ w0, const float* __restrict__ b0,
    short* __restrict__ w0p)
{
    int idx = blockIdx.x * 256 + threadIdx.x;
    if (idx >= 4 * 64 * 8) return;
    int j = idx & 7;
    int nn = (idx >> 3) & 63;
    int s = idx >> 9;
    short out = 0;
    if (s < 3) {
        float wv = w0[j * F + nn];
        __hip_bfloat16 hb = __float2bfloat16(wv);
        if (s < 2)      out = (short)__bfloat16_as_ushort(hb);
        else            out = bf16_bits(wv - __bfloat162float(hb));
    } else {
        float bv = b0[nn];
        __hip_bfloat16 hb = __float2bfloat16(bv);
        if (j == 0)      out = (short)__bfloat16_as_ushort(hb);
        else if (j == 1) out = bf16_bits(bv - __bfloat162float(hb));
    }
    w0p[idx] = out;
}

// ---------------------------------------------------------------------------
// MFMA implicit-GEMM 3x3 conv, SAME, Cout=128.
// R18: barrier-free, LDS-free, direct-L1/L2 operand streaming.
// R12-R17 evidence: staged structure's pipes sum serially (MFMA 70k + ds 52k
// + VALU 52k cyc/CU vs 227k dur); barrier-locked waves hit the same pipe
// simultaneously and staging VALU/drains fill the rest. Per-pass working
// sets (input 24.6KB, weights 8KB/tap) FIT IN L1 -> read operands directly.
// Addressing: y-padded layout (YP=248, yi=gy+1, halos zeroed) kills per-lane
// bounds checks; 18 precomputed per-lane 32-bit offsets [kh][kw][mt]
// (compile-time indexed); wave-uniform x-OOB select to a zeropad region;
// ci offsets are compile-time immediates. K-loop = pure {4 loads + 4 MFMA},
// zero barriers -> waves fully phase-independent, loads hoistable deep.
// Junk rows (m>=62) read in-slab garbage, masked at write (as before).
// ---------------------------------------------------------------------------
template<int CIN, bool FUSE>
__global__ __launch_bounds__(512, 2) void conv_mfma(
    const __hip_bfloat16* __restrict__ in,    // [B][NX][YP][CIN] bf16, padded
    const __hip_bfloat16* __restrict__ wt,    // [9][CIN/16][128][16] bf16
    const float* __restrict__ bias,           // [128]
    const float* __restrict__ w2,             // [128] (FUSE)
    const float* __restrict__ b2,             // [1]   (FUSE)
    int zoff,                                 // zeropad offset from `in`, shorts
    __hip_bfloat16* __restrict__ out_bf,      // [B][NX][YP][C1] padded (!FUSE)
    float* __restrict__ out_f)                // [B][NX][NY] (FUSE)
{
    constexpr int NPASS = CIN / 32;
    __shared__ float sred[FUSE ? 2 : 1][4][64];

    int tid  = threadIdx.x;
    int wave = tid >> 6;       // 0..7
    int lane = tid & 63;
    int mr = lane & 31;
    int g  = lane >> 5;
    int coh = wave & 1;        // cout half
    int xr  = wave >> 1;       // output x-row within quad (0..3)
    int x0 = blockIdx.x * 4;
    int y0 = blockIdx.y * 62;  // 0,62,124,186->178 (overlap benign)
    if (y0 > 178) y0 = 178;
    int b  = blockIdx.z;
    int n0 = coh * 64;

    const short* inp = (const short*)in;
    const short* wts = (const short*)wt;

    // 18 per-lane input offsets (shorts): [kh][kw][mt]; compile-time indexed.
    int voff[3][3][2];
#pragma unroll
    for (int kh = 0; kh < 3; kh++) {
        int gx = x0 - 1 + xr + kh;
        bool xok = (gx >= 0 && gx < NX);
#pragma unroll
        for (int kw = 0; kw < 3; kw++)
#pragma unroll
            for (int mt = 0; mt < 2; mt++) {
                int yi = y0 + kw + mr + 32 * mt;     // [0, 243] always in-slab
                voff[kh][kw][mt] = xok
                    ? (((b * NX + gx) * YP + yi) * CIN + g * 8)
                    : (zoff + lane * 8);
            }
    }
    int wlane = (n0 + mr) * 16 + g * 8;

    f32x16 acc[2][2];
#pragma unroll
    for (int mt = 0; mt < 2; mt++)
#pragma unroll
        for (int nt = 0; nt < 2; nt++)
            acc[mt][nt] = (f32x16){0,0,0,0,0,0,0,0,0,0,0,0,0,0,0,0};

#pragma unroll
    for (int p = 0; p < NPASS; p++) {
#pragma unroll
        for (int tap = 0; tap < 9; tap++) {
            const int kh = tap / 3, kw = tap % 3;
#pragma unroll
            for (int c0 = 0; c0 < 2; c0++) {
                const int wu  = (tap * (CIN / 16) + p * 2 + c0) * 2048;  // shorts
                const int cio = p * 32 + c0 * 16;                        // shorts
                short8 w0f = *(const short8*)(wts + wu + wlane);
                short8 w1f = *(const short8*)(wts + wu + wlane + 512);
                short8 a0  = *(const short8*)(inp + voff[kh][kw][0] + cio);
                short8 a1  = *(const short8*)(inp + voff[kh][kw][1] + cio);
                acc[0][0] = __builtin_amdgcn_mfma_f32_32x32x16_bf16(a0, w0f, acc[0][0], 0, 0, 0);
                acc[0][1] = __builtin_amdgcn_mfma_f32_32x32x16_bf16(a0, w1f, acc[0][1], 0, 0, 0);
                acc[1][0] = __builtin_amdgcn_mfma_f32_32x32x16_bf16(a1, w0f, acc[1][0], 0, 0, 0);
                acc[1][1] = __builtin_amdgcn_mfma_f32_32x32x16_bf16(a1, w1f, acc[1][1], 0, 0, 0);
            }
        }
    }

    // ---- epilogue (C-rows >= 62 are junk: masked) ----
    float bv0 = bias[n0 + mr];
    float bv1 = bias[n0 + 32 + mr];
    if (!FUSE) {
        size_t base = ((size_t)b * NX + (x0 + xr)) * YP;
#pragma unroll
        for (int mt = 0; mt < 2; mt++) {
#pragma unroll
            for (int r = 0; r < 16; r++) {
                int row = mt * 32 + (r & 3) + 8 * (r >> 2) + 4 * g;
                if (row < 62) {
                    int yi = y0 + row + 1;
                    out_bf[(base + yi) * C1 + n0 + mr]      = __float2bfloat16(tanh_fast(acc[mt][0][r] + bv0));
                    out_bf[(base + yi) * C1 + n0 + 32 + mr] = __float2bfloat16(tanh_fast(acc[mt][1][r] + bv1));
                }
            }
        }
    } else {
        float w20 = w2[n0 + mr];
        float w21 = w2[n0 + 32 + mr];
#pragma unroll
        for (int mt = 0; mt < 2; mt++) {
#pragma unroll
            for (int r = 0; r < 16; r++) {
                float v = tanh_fast(acc[mt][0][r] + bv0) * w20
                        + tanh_fast(acc[mt][1][r] + bv1) * w21;
                v += __shfl_xor(v, 1, 64);
                v += __shfl_xor(v, 2, 64);
                v += __shfl_xor(v, 4, 64);
                v += __shfl_xor(v, 8, 64);
                v += __shfl_xor(v, 16, 64);
                if (mr == 0)
                    sred[coh][xr][mt * 32 + (r & 3) + 8 * (r >> 2) + 4 * g] = v;
            }
        }
        __syncthreads();
        if (tid < 256) {
            int xr2 = tid >> 6;   // 0..3
            int yy  = tid & 63;
            if (yy < 62) {
                float r = sred[0][xr2][yy] + sred[1][xr2][yy] + b2[0];
                out_f[((size_t)b * NX + (x0 + xr2)) * NY + (y0 + yy)] = fmaxf(r, 0.f);
            }
        }
    }
}

// ---------------------------------------------------------------------------
extern "C" void kernel_launch(void* const* d_in, const int* in_sizes, int n_in,
                              void* d_out, int out_size, void* d_ws, size_t ws_size,
                              hipStream_t stream) {
    const float* pillars = (const float*)d_in[0];
    const int*   idxs    = (const int*)d_in[1];
    const float* pn_w0   = (const float*)d_in[4];
    const float* pn_b0   = (const float*)d_in[5];
    const float* pn_w1   = (const float*)d_in[6];
    const float* pn_b1   = (const float*)d_in[7];
    const float* cw0     = (const float*)d_in[8];
    const float* cb0     = (const float*)d_in[9];
    const float* cw1     = (const float*)d_in[10];
    const float* cb1     = (const float*)d_in[11];
    const float* cw2     = (const float*)d_in[12];
    const float* cb2     = (const float*)d_in[13];
    float* out = (float*)d_out;

    // workspace layout (padded images)
    char* ws = (char*)d_ws;
    const size_t IMG_BYTES  = (size_t)B * NX * YP * F * 2;    // 30.47 MB
    const size_t OUT1_BYTES = (size_t)B * NX * YP * C1 * 2;   // 60.95 MB
    const size_t WIN_BYTES  = (size_t)B * NX * NY * 4;
    const size_t WT1_BYTES  = (size_t)9 * C1 * F * 2;
    const size_t WT2_BYTES  = (size_t)9 * C1 * C1 * 2;
    const size_t W1T_BYTES  = (size_t)F * F * 2;
    const size_t W0P_BYTES  = (size_t)4 * 64 * 8 * 2;
    __hip_bfloat16* img  = (__hip_bfloat16*)ws;
    __hip_bfloat16* out1 = (__hip_bfloat16*)(ws + IMG_BYTES);
    int*   winner = (int*)(ws + IMG_BYTES + OUT1_BYTES);
    __hip_bfloat16* wt1 = (__hip_bfloat16*)(ws + IMG_BYTES + OUT1_BYTES + WIN_BYTES);
    __hip_bfloat16* wt2 = (__hip_bfloat16*)(ws + IMG_BYTES + OUT1_BYTES + WIN_BYTES + WT1_BYTES);
    __hip_bfloat16* w1t = (__hip_bfloat16*)(ws + IMG_BYTES + OUT1_BYTES + WIN_BYTES + WT1_BYTES + WT2_BYTES);
    short* w0p = (short*)(ws + IMG_BYTES + OUT1_BYTES + WIN_BYTES + WT1_BYTES + WT2_BYTES + W1T_BYTES);
    __hip_bfloat16* zeropad = (__hip_bfloat16*)(ws + IMG_BYTES + OUT1_BYTES + WIN_BYTES + WT1_BYTES + WT2_BYTES + W1T_BYTES + W0P_BYTES);

    int zoff1 = (int)((short*)zeropad - (short*)img);    // conv1 x-OOB target
    int zoff2 = (int)((short*)zeropad - (short*)out1);   // conv2 x-OOB target

    hipMemsetAsync(img, 0, IMG_BYTES, stream);
    hipMemsetAsync(winner, 0xFF, WIN_BYTES, stream);   // -1
    hipMemsetAsync(zeropad, 0, 4096, stream);

    cvt_w_kernel<<<(9 * F * C1 + 255) / 256, 256, 0, stream>>>(cw0, wt1, F);
    cvt_w_kernel<<<(9 * C1 * C1 + 255) / 256, 256, 0, stream>>>(cw1, wt2, C1);
    cvt_w1_kernel<<<(F * F + 255) / 256, 256, 0, stream>>>(pn_w1, w1t);
    cvt_w0p_kernel<<<(4 * 64 * 8 + 255) / 256, 256, 0, stream>>>(pn_w0, pn_b0, w0p);
    halo_kernel<<<(B * NX * 4 * (C1 / 8) + 255) / 256, 256, 0, stream>>>(out1);

    winner_kernel<<<(B * P + 255) / 256, 256, 0, stream>>>(idxs, winner);
    pn_mfma_kernel<<<B * P, 128, 0, stream>>>(pillars, w0p, w1t, pn_b1,
                                              idxs, winner, img);

    conv_mfma<F, false><<<dim3(NX / 4, 4, B), 512, 0, stream>>>(
        img, wt1, cb0, nullptr, nullptr, zoff1, out1, nullptr);
    conv_mfma<C1, true><<<dim3(NX / 4, 4, B), 512, 0, stream>>>(
        out1, wt2, cb1, cw2, cb2, zoff2, nullptr, out);
}

// Round 7
// 372.207 us; speedup vs baseline: 1.3466x; 1.3466x over previous
//
#include <hip/hip_runtime.h>
#include <hip/hip_bf16.h>
#include <math.h>

// Problem constants (fixed by setup_inputs)
#define B  4
#define P  5000
#define NPT 100
#define F  64          // pointnet feature dim
#define NX 240
#define NY 240
#define C1 128         // conv1/conv2 out channels

typedef __attribute__((ext_vector_type(8)))  short short8;   // 8 bf16
typedef __attribute__((ext_vector_type(16))) float f32x16;

// tanh via v_exp + v_rcp (rel err ~1e-6; saturates correctly at +-1)
__device__ __forceinline__ float tanh_fast(float x) {
    float e = exp2f(x * 2.8853900817779268f);   // 2*log2(e): single v_exp
    float r = __builtin_amdgcn_rcpf(e + 1.0f);
    return __builtin_fmaf(-2.0f, r, 1.0f);
}
__device__ __forceinline__ short bf16_bits(float f) {
    return (short)(__bfloat16_as_ushort(__float2bfloat16(f)));
}
// async 16B global->LDS: wave-uniform LDS base + lane*16
__device__ __forceinline__ void async_load16(const void* g, void* l) {
    __builtin_amdgcn_global_load_lds(
        (const __attribute__((address_space(1))) void*)g,
        (__attribute__((address_space(3))) void*)l, 16, 0, 0);
}

// ---------------------------------------------------------------------------
// PointNet, both layers on MFMA — R17 register-resident handoff (proven).
// ---------------------------------------------------------------------------
__global__ __launch_bounds__(128, 2) void pn_mfma_kernel(
    const float* __restrict__ pillars,    // [B,P,N,8]
    const short* __restrict__ w0p,        // [4 slots][64 feat][8 j] bf16 bits
    const __hip_bfloat16* __restrict__ w1t, // [64 n][64 k-permuted] bf16
    const float* __restrict__ b1,         // [64]
    const int* __restrict__ idxs,         // [B*P][2]
    const int* __restrict__ winner,       // [B*NX*NY]
    __hip_bfloat16* __restrict__ img)     // [B*NX*NY][F]
{
    constexpr int XS = 40;                // 80B row: bank stride 20 -> max 4-way
    __shared__ short xA[128 * XS];        // 10,240 B
    __shared__ float red[2][F];
    __shared__ unsigned int vb32[4];

    int bp = blockIdx.x;
    int n  = threadIdx.x;
    int wave = n >> 6, lane = n & 63;
    int mr = lane & 31;
    int g  = lane >> 5;
    bool live = (n < NPT);

    const float* xp = pillars + ((size_t)bp * NPT + (live ? n : 0)) * 8;
    float4 q0 = *(const float4*)xp;
    float4 q1 = *(const float4*)(xp + 4);
    float x[8] = {q0.x, q0.y, q0.z, q0.w, q1.x, q1.y, q1.z, q1.w};

    float ss = 0.f;
#pragma unroll
    for (int c = 0; c < 8; c++) ss += x[c] * x[c];
    bool valid = live && (ss < 1e12f);

    unsigned long long bal = __ballot(valid);
    if (lane == 0) {
        vb32[wave * 2]     = (unsigned)bal;
        vb32[wave * 2 + 1] = (unsigned)(bal >> 32);
    }

    short8 xhi, xlo, xone;
#pragma unroll
    for (int c = 0; c < 8; c++) {
        __hip_bfloat16 hb = __float2bfloat16(x[c]);
        float hv = __bfloat162float(hb);
        xhi[c] = (short)__bfloat16_as_ushort(hb);
        xlo[c] = bf16_bits(x[c] - hv);
        xone[c] = (c < 2) ? bf16_bits(1.0f) : (short)0;   // one-hot for bias hi+lo
    }
    *(short8*)&xA[n * XS + 0]  = xhi;
    *(short8*)&xA[n * XS + 8]  = xlo;
    *(short8*)&xA[n * XS + 16] = xhi;
    *(short8*)&xA[n * XS + 24] = xone;
    __syncthreads();

    // A-frags: weight rows. slots: kk0g0=w_hi (x_hi), kk0g1=w_hi (x_lo),
    // kk1g0=w_lo (x_hi), kk1g1=bias hi/lo (x one-hot).
    short8 wb[2][2];
#pragma unroll
    for (int kk = 0; kk < 2; kk++)
#pragma unroll
        for (int m = 0; m < 2; m++)
            wb[kk][m] = *(const short8*)(w0p + ((kk * 2 + g) * 64 + m * 32 + mr) * 8);

    f32x16 acc1[2][2];
#pragma unroll
    for (int ptt = 0; ptt < 2; ptt++)
#pragma unroll
        for (int m = 0; m < 2; m++)
            acc1[ptt][m] = (f32x16){0,0,0,0,0,0,0,0,0,0,0,0,0,0,0,0};

#pragma unroll
    for (int kk = 0; kk < 2; kk++) {
        short8 x0 = *(const short8*)&xA[(wave * 64 + mr) * XS + kk * 16 + g * 8];
        short8 x1 = *(const short8*)&xA[(wave * 64 + 32 + mr) * XS + kk * 16 + g * 8];
        acc1[0][0] = __builtin_amdgcn_mfma_f32_32x32x16_bf16(wb[kk][0], x0, acc1[0][0], 0, 0, 0);
        acc1[0][1] = __builtin_amdgcn_mfma_f32_32x32x16_bf16(wb[kk][1], x0, acc1[0][1], 0, 0, 0);
        acc1[1][0] = __builtin_amdgcn_mfma_f32_32x32x16_bf16(wb[kk][0], x1, acc1[1][0], 0, 0, 0);
        acc1[1][1] = __builtin_amdgcn_mfma_f32_32x32x16_bf16(wb[kk][1], x1, acc1[1][1], 0, 0, 0);
    }

    // tanh + pack in-register: afrag[ptt][c0][j] = tanh(acc1[c0>>1][8*(c0&1)+j])
    short8 afrag[2][4];
#pragma unroll
    for (int ptt = 0; ptt < 2; ptt++) {
#pragma unroll
        for (int c0 = 0; c0 < 4; c0++) {
            short8 t;
#pragma unroll
            for (int j = 0; j < 8; j++) {
                float v = (c0 >> 1) ? acc1[ptt][1][8 * (c0 & 1) + j]
                                    : acc1[ptt][0][8 * (c0 & 1) + j];
                t[j] = bf16_bits(tanh_fast(v));
            }
            afrag[ptt][c0] = t;
        }
    }

    short8 bfrag[2][4];
#pragma unroll
    for (int nt = 0; nt < 2; nt++)
#pragma unroll
        for (int c0 = 0; c0 < 4; c0++)
            bfrag[nt][c0] = *(const short8*)((const short*)w1t +
                                (nt * 32 + mr) * F + c0 * 16 + g * 8);

    f32x16 a2[2][2];   // [ptt][nt]
#pragma unroll
    for (int ptt = 0; ptt < 2; ptt++)
#pragma unroll
        for (int nt = 0; nt < 2; nt++)
            a2[ptt][nt] = (f32x16){0,0,0,0,0,0,0,0,0,0,0,0,0,0,0,0};

#pragma unroll
    for (int c0 = 0; c0 < 4; c0++) {
        a2[0][0] = __builtin_amdgcn_mfma_f32_32x32x16_bf16(afrag[0][c0], bfrag[0][c0], a2[0][0], 0, 0, 0);
        a2[0][1] = __builtin_amdgcn_mfma_f32_32x32x16_bf16(afrag[0][c0], bfrag[1][c0], a2[0][1], 0, 0, 0);
        a2[1][0] = __builtin_amdgcn_mfma_f32_32x32x16_bf16(afrag[1][c0], bfrag[0][c0], a2[1][0], 0, 0, 0);
        a2[1][1] = __builtin_amdgcn_mfma_f32_32x32x16_bf16(afrag[1][c0], bfrag[1][c0], a2[1][1], 0, 0, 0);
    }

    float bv0 = b1[mr];
    float bv1 = b1[32 + mr];
    bool allv = ((vb32[0] & vb32[1] & vb32[2]) == 0xFFFFFFFFu) &&
                ((vb32[3] & 0xFu) == 0xFu);
    float mx0 = -INFINITY, mx1 = -INFINITY;

    if (allv) {
#pragma unroll
        for (int ptt = 0; ptt < 2; ptt++) {
#pragma unroll
            for (int r = 0; r < 16; r++) {
                bool inc = !(wave == 1 && ptt == 1) || (g == 0 && r < 4);
                if (inc) {
                    mx0 = fmaxf(mx0, (ptt == 0) ? a2[0][0][r] : a2[1][0][r]);
                    mx1 = fmaxf(mx1, (ptt == 0) ? a2[0][1][r] : a2[1][1][r]);
                }
            }
        }
        mx0 += bv0;
        mx1 += bv1;
    } else {
        unsigned wm0 = vb32[wave * 2];
        unsigned wm1 = vb32[wave * 2 + 1];
#pragma unroll
        for (int ptt = 0; ptt < 2; ptt++) {
            unsigned wm = (ptt == 0) ? wm0 : wm1;
#pragma unroll
            for (int r = 0; r < 16; r++) {
                int idx = (r & 3) + 8 * (r >> 2) + 4 * g;
                bool inc = !(wave == 1 && ptt == 1) || (idx < 4);
                if (inc) {
                    bool vbit = (wm >> idx) & 1;
                    float a0 = (ptt == 0) ? a2[0][0][r] : a2[1][0][r];
                    float a1 = (ptt == 0) ? a2[0][1][r] : a2[1][1][r];
                    mx0 = fmaxf(mx0, vbit ? (a0 + bv0) : 0.0f);
                    mx1 = fmaxf(mx1, vbit ? (a1 + bv1) : 0.0f);
                }
            }
        }
    }
    mx0 = fmaxf(mx0, __shfl_xor(mx0, 32, 64));
    mx1 = fmaxf(mx1, __shfl_xor(mx1, 32, 64));
    if (lane < 32) { red[wave][mr] = mx0; red[wave][32 + mr] = mx1; }
    __syncthreads();
    if (n < F) {
        float v = fmaxf(red[0][n], red[1][n]);
        int ix = idxs[bp * 2], iy = idxs[bp * 2 + 1];
        int b = bp / P, p = bp % P;
        int cell = (b * NX + ix) * NY + iy;
        if (winner[cell] == p)
            img[(size_t)cell * F + n] = __float2bfloat16(v);
    }
}

// ---------------------------------------------------------------------------
// Scatter winner: numpy last-write-wins via atomicMax(p). Runs BEFORE pn.
// ---------------------------------------------------------------------------
__global__ __launch_bounds__(256) void winner_kernel(
    const int* __restrict__ idxs, int* __restrict__ winner)
{
    int i = blockIdx.x * 256 + threadIdx.x;
    if (i >= B * P) return;
    int ix = idxs[i * 2], iy = idxs[i * 2 + 1];
    int b = i / P, p = i % P;
    atomicMax(&winner[(b * NX + ix) * NY + iy], p);
}

// ---------------------------------------------------------------------------
// Weight converts. Conv weights -> [tap][ci/16][128 co][16 ci] bf16.
// ---------------------------------------------------------------------------
__global__ __launch_bounds__(256) void cvt_w_kernel(
    const float* __restrict__ w, __hip_bfloat16* __restrict__ wt, int cin)
{
    int idx = blockIdx.x * 256 + threadIdx.x;
    int total = 9 * cin * 128;
    if (idx >= total) return;
    int co = idx % 128;
    int rest = idx / 128;
    int ci = rest % cin;
    int t  = rest / cin;
    int c0 = ci >> 4, c16 = ci & 15;
    wt[(((size_t)(t * (cin >> 4) + c0)) * 128 + co) * 16 + c16] = __float2bfloat16(w[idx]);
}

// w1 [64 k][64 n] fp32 -> w1t [n][kk'] bf16 with k-permutation
// kk' = c0*16+g*8+j  ->  k = 16*c0 + 4*g + (j&3) + 8*(j>>2)
__global__ __launch_bounds__(256) void cvt_w1_kernel(
    const float* __restrict__ w1, __hip_bfloat16* __restrict__ w1t)
{
    int idx = blockIdx.x * 256 + threadIdx.x;
    if (idx >= F * F) return;
    int nn = idx >> 6, kk = idx & 63;
    int c0 = kk >> 4, g = (kk >> 3) & 1, j = kk & 7;
    int k = 16 * c0 + 4 * g + (j & 3) + 8 * (j >> 2);
    w1t[nn * F + kk] = __float2bfloat16(w1[k * F + nn]);
}

// w0 [8,64] fp32 + b0 [64] -> w0p [4 slots][64 feat][8 j] bf16 bits.
// slots 0,1 = w_hi; slot 2 = w_lo; slot 3 = bias (j=0: hi, j=1: lo).
__global__ __launch_bounds__(256) void cvt_w0p_kernel(
    const float* __restrict__ w0, const float* __restrict__ b0,
    short* __restrict__ w0p)
{
    int idx = blockIdx.x * 256 + threadIdx.x;
    if (idx >= 4 * 64 * 8) return;
    int j = idx & 7;
    int nn = (idx >> 3) & 63;
    int s = idx >> 9;
    short out = 0;
    if (s < 3) {
        float wv = w0[j * F + nn];
        __hip_bfloat16 hb = __float2bfloat16(wv);
        if (s < 2)      out = (short)__bfloat16_as_ushort(hb);
        else            out = bf16_bits(wv - __bfloat162float(hb));
    } else {
        float bv = b0[nn];
        __hip_bfloat16 hb = __float2bfloat16(bv);
        if (j == 0)      out = (short)__bfloat16_as_ushort(hb);
        else if (j == 1) out = bf16_bits(bv - __bfloat162float(hb));
    }
    w0p[idx] = out;
}

// ---------------------------------------------------------------------------
// MFMA implicit-GEMM 3x3 conv, SAME, Cout=128 — R16 staged structure
// (proven 94.7us) + T5 s_setprio around MFMA quads.
// R18 post-mortem: direct-L1 gather (no LDS) was latency-bound (64 distinct
// lines per A-load); LDS staging IS the coalescing engine. Keep it.
// setprio mechanism: 2-3 independently-phased blocks/CU; boosting the wave
// entering its MFMA quad keeps the matrix pipe fed while sibling blocks'
// waves do staging/VALU (catalog T5: +4-7% attn-like, null on lockstep).
// ---------------------------------------------------------------------------
template<int CIN, bool FUSE>
__global__ __launch_bounds__(512, 2) void conv_mfma(
    const __hip_bfloat16* __restrict__ in,    // [B,240,240,CIN] bf16
    const __hip_bfloat16* __restrict__ wt,    // [9][CIN/16][128][16] bf16
    const float* __restrict__ bias,           // [128]
    const float* __restrict__ w2,             // [128] (FUSE)
    const float* __restrict__ b2,             // [1]   (FUSE)
    const __hip_bfloat16* __restrict__ zerobuf, // >=16B of zeros
    __hip_bfloat16* __restrict__ out_bf,
    float* __restrict__ out_f)
{
    constexpr int NPASS = CIN / 32;       // 32 ci per pass
    constexpr int NC16  = 2;              // 16-ci granules per pass
    constexpr int CSTR  = 400;            // column stride in granules (6*64+16)
    __shared__ short sP[2][4 * CSTR * 8]; // 2 x 25,600 B = 51,200 B
    __shared__ float sred[FUSE ? 2 : 1][4][64];

    int tid  = threadIdx.x;
    int wave = tid >> 6;       // 0..7
    int lane = tid & 63;
    int mr = lane & 31;
    int g  = lane >> 5;
    int coh = wave & 1;        // cout half
    int xr  = wave >> 1;       // output x-row within quad (0..3)
    int x0 = blockIdx.x * 4;
    int y0 = blockIdx.y * 62;  // 0,62,124,186->178 (overlap benign)
    if (y0 > 178) y0 = 178;
    int b  = blockIdx.z;
    int n0 = coh * 64;

    const short* wts = (const short*)wt;

    // stage pass pp into dst: 24 (cc,dx) chunks of 1KB, 3 per wave
    auto stage = [&](int pp, short* dst) {
        int gy = y0 - 1 + lane;              // dy = lane, 0..63
        bool yok = (gy >= 0 && gy < NY);
#pragma unroll
        for (int j = 0; j < 3; j++) {
            int q  = j * 8 + wave;           // 0..23
            int cc = q & 3;                  // ci granule 0..3
            int dx = q >> 2;                 // staged x-row 0..5
            int gx = x0 - 1 + dx;
            const __hip_bfloat16* src =
                (yok && gx >= 0 && gx < NX)
                ? &in[(((size_t)b * NX + gx) * NY + gy) * CIN + pp * 32 + cc * 8]
                : zerobuf;
            async_load16(src, (void*)(dst + (cc * CSTR + dx * 64) * 8));
        }
    };

    f32x16 acc[2][2];
#pragma unroll
    for (int mt = 0; mt < 2; mt++)
#pragma unroll
        for (int nt = 0; nt < 2; nt++)
            acc[mt][nt] = (f32x16){0,0,0,0,0,0,0,0,0,0,0,0,0,0,0,0};

    stage(0, sP[0]);

#pragma unroll
    for (int p = 0; p < NPASS; p++) {
        __syncthreads();     // drains own vmcnt: pass p's staging landed
        if (p + 1 < NPASS)
            stage(p + 1, sP[(p + 1) & 1]);   // in flight during compute(p)
        const short* sPb = sP[p & 1];

        // ---- K-loop: 9 taps x 2 ci-granule-pairs, weights streamed from L2
#pragma unroll
        for (int tap = 0; tap < 9; tap++) {
            int kh = tap / 3, kw = tap % 3;
            int rowcol = (xr + kh) * 64 + kw;
            const short* wrow = wts + ((size_t)(tap * (CIN / 16) + p * NC16) * 128 + n0 + mr) * 16 + g * 8;
#pragma unroll
            for (int c0 = 0; c0 < NC16; c0++) {
                short8 w0f = *(const short8*)(wrow + (size_t)c0 * 2048);
                short8 w1f = *(const short8*)(wrow + (size_t)c0 * 2048 + 512);
                int cc = c0 * 2 + g;
                const short* abase = sPb + (cc * CSTR + rowcol + mr) * 8;
                short8 a0 = *(const short8*)(abase);
                short8 a1 = *(const short8*)(abase + 32 * 8);   // +32 rows
                __builtin_amdgcn_s_setprio(1);
                acc[0][0] = __builtin_amdgcn_mfma_f32_32x32x16_bf16(a0, w0f, acc[0][0], 0, 0, 0);
                acc[0][1] = __builtin_amdgcn_mfma_f32_32x32x16_bf16(a0, w1f, acc[0][1], 0, 0, 0);
                acc[1][0] = __builtin_amdgcn_mfma_f32_32x32x16_bf16(a1, w0f, acc[1][0], 0, 0, 0);
                acc[1][1] = __builtin_amdgcn_mfma_f32_32x32x16_bf16(a1, w1f, acc[1][1], 0, 0, 0);
                __builtin_amdgcn_s_setprio(0);
            }
        }
    }

    // ---- epilogue (C-rows >= 62 are junk: masked) ----
    float bv0 = bias[n0 + mr];
    float bv1 = bias[n0 + 32 + mr];
    if (!FUSE) {
        size_t base = ((size_t)b * NX + (x0 + xr)) * NY;
#pragma unroll
        for (int mt = 0; mt < 2; mt++) {
#pragma unroll
            for (int r = 0; r < 16; r++) {
                int row = mt * 32 + (r & 3) + 8 * (r >> 2) + 4 * g;
                if (row < 62) {
                    int y = y0 + row;
                    out_bf[(base + y) * C1 + n0 + mr]      = __float2bfloat16(tanh_fast(acc[mt][0][r] + bv0));
                    out_bf[(base + y) * C1 + n0 + 32 + mr] = __float2bfloat16(tanh_fast(acc[mt][1][r] + bv1));
                }
            }
        }
    } else {
        float w20 = w2[n0 + mr];
        float w21 = w2[n0 + 32 + mr];
#pragma unroll
        for (int mt = 0; mt < 2; mt++) {
#pragma unroll
            for (int r = 0; r < 16; r++) {
                float v = tanh_fast(acc[mt][0][r] + bv0) * w20
                        + tanh_fast(acc[mt][1][r] + bv1) * w21;
                v += __shfl_xor(v, 1, 64);
                v += __shfl_xor(v, 2, 64);
                v += __shfl_xor(v, 4, 64);
                v += __shfl_xor(v, 8, 64);
                v += __shfl_xor(v, 16, 64);
                if (mr == 0)
                    sred[coh][xr][mt * 32 + (r & 3) + 8 * (r >> 2) + 4 * g] = v;
            }
        }
        __syncthreads();
        if (tid < 256) {
            int xr2 = tid >> 6;   // 0..3
            int yy  = tid & 63;
            if (yy < 62) {
                float r = sred[0][xr2][yy] + sred[1][xr2][yy] + b2[0];
                out_f[((size_t)b * NX + (x0 + xr2)) * NY + (y0 + yy)] = fmaxf(r, 0.f);
            }
        }
    }
}

// ---------------------------------------------------------------------------
extern "C" void kernel_launch(void* const* d_in, const int* in_sizes, int n_in,
                              void* d_out, int out_size, void* d_ws, size_t ws_size,
                              hipStream_t stream) {
    const float* pillars = (const float*)d_in[0];
    const int*   idxs    = (const int*)d_in[1];
    const float* pn_w0   = (const float*)d_in[4];
    const float* pn_b0   = (const float*)d_in[5];
    const float* pn_w1   = (const float*)d_in[6];
    const float* pn_b1   = (const float*)d_in[7];
    const float* cw0     = (const float*)d_in[8];
    const float* cb0     = (const float*)d_in[9];
    const float* cw1     = (const float*)d_in[10];
    const float* cb1     = (const float*)d_in[11];
    const float* cw2     = (const float*)d_in[12];
    const float* cb2     = (const float*)d_in[13];
    float* out = (float*)d_out;

    // workspace layout
    char* ws = (char*)d_ws;
    const size_t IMG_BYTES  = (size_t)B * NX * NY * F * 2;
    const size_t OUT1_BYTES = (size_t)B * NX * NY * C1 * 2;
    const size_t WIN_BYTES  = (size_t)B * NX * NY * 4;
    const size_t PMAX_BYTES = (size_t)B * P * F * 4;   // (unused since R17)
    const size_t WT1_BYTES  = (size_t)9 * C1 * F * 2;
    const size_t WT2_BYTES  = (size_t)9 * C1 * C1 * 2;
    const size_t W1T_BYTES  = (size_t)F * F * 2;
    const size_t W0P_BYTES  = (size_t)4 * 64 * 8 * 2;
    __hip_bfloat16* img  = (__hip_bfloat16*)ws;
    __hip_bfloat16* out1 = (__hip_bfloat16*)(ws + IMG_BYTES);
    int*   winner = (int*)(ws + IMG_BYTES + OUT1_BYTES);
    __hip_bfloat16* wt1 = (__hip_bfloat16*)(ws + IMG_BYTES + OUT1_BYTES + WIN_BYTES + PMAX_BYTES);
    __hip_bfloat16* wt2 = (__hip_bfloat16*)(ws + IMG_BYTES + OUT1_BYTES + WIN_BYTES + PMAX_BYTES + WT1_BYTES);
    __hip_bfloat16* w1t = (__hip_bfloat16*)(ws + IMG_BYTES + OUT1_BYTES + WIN_BYTES + PMAX_BYTES + WT1_BYTES + WT2_BYTES);
    short* w0p = (short*)(ws + IMG_BYTES + OUT1_BYTES + WIN_BYTES + PMAX_BYTES + WT1_BYTES + WT2_BYTES + W1T_BYTES);
    __hip_bfloat16* zerobuf = (__hip_bfloat16*)(ws + IMG_BYTES + OUT1_BYTES + WIN_BYTES + PMAX_BYTES + WT1_BYTES + WT2_BYTES + W1T_BYTES + W0P_BYTES);

    hipMemsetAsync(img, 0, IMG_BYTES, stream);
    hipMemsetAsync(winner, 0xFF, WIN_BYTES, stream);   // -1
    hipMemsetAsync(zerobuf, 0, 64, stream);            // OOB target for async staging

    cvt_w_kernel<<<(9 * F * C1 + 255) / 256, 256, 0, stream>>>(cw0, wt1, F);
    cvt_w_kernel<<<(9 * C1 * C1 + 255) / 256, 256, 0, stream>>>(cw1, wt2, C1);
    cvt_w1_kernel<<<(F * F + 255) / 256, 256, 0, stream>>>(pn_w1, w1t);
    cvt_w0p_kernel<<<(4 * 64 * 8 + 255) / 256, 256, 0, stream>>>(pn_w0, pn_b0, w0p);

    winner_kernel<<<(B * P + 255) / 256, 256, 0, stream>>>(idxs, winner);
    pn_mfma_kernel<<<B * P, 128, 0, stream>>>(pillars, w0p, w1t, pn_b1,
                                              idxs, winner, img);

    conv_mfma<F, false><<<dim3(NX / 4, 4, B), 512, 0, stream>>>(
        img, wt1, cb0, nullptr, nullptr, zerobuf, out1, nullptr);
    conv_mfma<C1, true><<<dim3(NX / 4, 4, B), 512, 0, stream>>>(
        out1, wt2, cb1, cw2, cb2, zerobuf, nullptr, out);
}

// Round 8
// 329.839 us; speedup vs baseline: 1.5196x; 1.1284x over previous
//
#include <hip/hip_runtime.h>
#include <hip/hip_bf16.h>
#include <math.h>

// Problem constants (fixed by setup_inputs)
#define B  4
#define P  5000
#define NPT 100
#define F  64          // pointnet feature dim
#define NX 240
#define NY 240
#define C1 128         // conv1/conv2 out channels

typedef __attribute__((ext_vector_type(8)))  short short8;   // 8 bf16
typedef __attribute__((ext_vector_type(16))) float f32x16;

// tanh via v_exp + v_rcp (rel err ~1e-6; saturates correctly at +-1)
__device__ __forceinline__ float tanh_fast(float x) {
    float e = exp2f(x * 2.8853900817779268f);   // 2*log2(e): single v_exp
    float r = __builtin_amdgcn_rcpf(e + 1.0f);
    return __builtin_fmaf(-2.0f, r, 1.0f);
}
__device__ __forceinline__ short bf16_bits(float f) {
    return (short)(__bfloat16_as_ushort(__float2bfloat16(f)));
}
// async 16B global->LDS: wave-uniform LDS base + lane*16
__device__ __forceinline__ void async_load16(const void* g, void* l) {
    __builtin_amdgcn_global_load_lds(
        (const __attribute__((address_space(1))) void*)g,
        (__attribute__((address_space(3))) void*)l, 16, 0, 0);
}

// ---------------------------------------------------------------------------
// PointNet, both layers on MFMA — R17 register-resident handoff (proven).
// ---------------------------------------------------------------------------
__global__ __launch_bounds__(128, 2) void pn_mfma_kernel(
    const float* __restrict__ pillars,    // [B,P,N,8]
    const short* __restrict__ w0p,        // [4 slots][64 feat][8 j] bf16 bits
    const __hip_bfloat16* __restrict__ w1t, // [64 n][64 k-permuted] bf16
    const float* __restrict__ b1,         // [64]
    const int* __restrict__ idxs,         // [B*P][2]
    const int* __restrict__ winner,       // [B*NX*NY]
    __hip_bfloat16* __restrict__ img)     // [B*NX*NY][F]
{
    constexpr int XS = 40;                // 80B row: bank stride 20 -> max 4-way
    __shared__ short xA[128 * XS];        // 10,240 B
    __shared__ float red[2][F];
    __shared__ unsigned int vb32[4];

    int bp = blockIdx.x;
    int n  = threadIdx.x;
    int wave = n >> 6, lane = n & 63;
    int mr = lane & 31;
    int g  = lane >> 5;
    bool live = (n < NPT);

    const float* xp = pillars + ((size_t)bp * NPT + (live ? n : 0)) * 8;
    float4 q0 = *(const float4*)xp;
    float4 q1 = *(const float4*)(xp + 4);
    float x[8] = {q0.x, q0.y, q0.z, q0.w, q1.x, q1.y, q1.z, q1.w};

    float ss = 0.f;
#pragma unroll
    for (int c = 0; c < 8; c++) ss += x[c] * x[c];
    bool valid = live && (ss < 1e12f);

    unsigned long long bal = __ballot(valid);
    if (lane == 0) {
        vb32[wave * 2]     = (unsigned)bal;
        vb32[wave * 2 + 1] = (unsigned)(bal >> 32);
    }

    short8 xhi, xlo, xone;
#pragma unroll
    for (int c = 0; c < 8; c++) {
        __hip_bfloat16 hb = __float2bfloat16(x[c]);
        float hv = __bfloat162float(hb);
        xhi[c] = (short)__bfloat16_as_ushort(hb);
        xlo[c] = bf16_bits(x[c] - hv);
        xone[c] = (c < 2) ? bf16_bits(1.0f) : (short)0;   // one-hot for bias hi+lo
    }
    *(short8*)&xA[n * XS + 0]  = xhi;
    *(short8*)&xA[n * XS + 8]  = xlo;
    *(short8*)&xA[n * XS + 16] = xhi;
    *(short8*)&xA[n * XS + 24] = xone;
    __syncthreads();

    // A-frags: weight rows. slots: kk0g0=w_hi (x_hi), kk0g1=w_hi (x_lo),
    // kk1g0=w_lo (x_hi), kk1g1=bias hi/lo (x one-hot).
    short8 wb[2][2];
#pragma unroll
    for (int kk = 0; kk < 2; kk++)
#pragma unroll
        for (int m = 0; m < 2; m++)
            wb[kk][m] = *(const short8*)(w0p + ((kk * 2 + g) * 64 + m * 32 + mr) * 8);

    f32x16 acc1[2][2];
#pragma unroll
    for (int ptt = 0; ptt < 2; ptt++)
#pragma unroll
        for (int m = 0; m < 2; m++)
            acc1[ptt][m] = (f32x16){0,0,0,0,0,0,0,0,0,0,0,0,0,0,0,0};

#pragma unroll
    for (int kk = 0; kk < 2; kk++) {
        short8 x0 = *(const short8*)&xA[(wave * 64 + mr) * XS + kk * 16 + g * 8];
        short8 x1 = *(const short8*)&xA[(wave * 64 + 32 + mr) * XS + kk * 16 + g * 8];
        acc1[0][0] = __builtin_amdgcn_mfma_f32_32x32x16_bf16(wb[kk][0], x0, acc1[0][0], 0, 0, 0);
        acc1[0][1] = __builtin_amdgcn_mfma_f32_32x32x16_bf16(wb[kk][1], x0, acc1[0][1], 0, 0, 0);
        acc1[1][0] = __builtin_amdgcn_mfma_f32_32x32x16_bf16(wb[kk][0], x1, acc1[1][0], 0, 0, 0);
        acc1[1][1] = __builtin_amdgcn_mfma_f32_32x32x16_bf16(wb[kk][1], x1, acc1[1][1], 0, 0, 0);
    }

    // tanh + pack in-register: afrag[ptt][c0][j] = tanh(acc1[c0>>1][8*(c0&1)+j])
    short8 afrag[2][4];
#pragma unroll
    for (int ptt = 0; ptt < 2; ptt++) {
#pragma unroll
        for (int c0 = 0; c0 < 4; c0++) {
            short8 t;
#pragma unroll
            for (int j = 0; j < 8; j++) {
                float v = (c0 >> 1) ? acc1[ptt][1][8 * (c0 & 1) + j]
                                    : acc1[ptt][0][8 * (c0 & 1) + j];
                t[j] = bf16_bits(tanh_fast(v));
            }
            afrag[ptt][c0] = t;
        }
    }

    short8 bfrag[2][4];
#pragma unroll
    for (int nt = 0; nt < 2; nt++)
#pragma unroll
        for (int c0 = 0; c0 < 4; c0++)
            bfrag[nt][c0] = *(const short8*)((const short*)w1t +
                                (nt * 32 + mr) * F + c0 * 16 + g * 8);

    f32x16 a2[2][2];   // [ptt][nt]
#pragma unroll
    for (int ptt = 0; ptt < 2; ptt++)
#pragma unroll
        for (int nt = 0; nt < 2; nt++)
            a2[ptt][nt] = (f32x16){0,0,0,0,0,0,0,0,0,0,0,0,0,0,0,0};

#pragma unroll
    for (int c0 = 0; c0 < 4; c0++) {
        a2[0][0] = __builtin_amdgcn_mfma_f32_32x32x16_bf16(afrag[0][c0], bfrag[0][c0], a2[0][0], 0, 0, 0);
        a2[0][1] = __builtin_amdgcn_mfma_f32_32x32x16_bf16(afrag[0][c0], bfrag[1][c0], a2[0][1], 0, 0, 0);
        a2[1][0] = __builtin_amdgcn_mfma_f32_32x32x16_bf16(afrag[1][c0], bfrag[0][c0], a2[1][0], 0, 0, 0);
        a2[1][1] = __builtin_amdgcn_mfma_f32_32x32x16_bf16(afrag[1][c0], bfrag[1][c0], a2[1][1], 0, 0, 0);
    }

    float bv0 = b1[mr];
    float bv1 = b1[32 + mr];
    bool allv = ((vb32[0] & vb32[1] & vb32[2]) == 0xFFFFFFFFu) &&
                ((vb32[3] & 0xFu) == 0xFu);
    float mx0 = -INFINITY, mx1 = -INFINITY;

    if (allv) {
#pragma unroll
        for (int ptt = 0; ptt < 2; ptt++) {
#pragma unroll
            for (int r = 0; r < 16; r++) {
                bool inc = !(wave == 1 && ptt == 1) || (g == 0 && r < 4);
                if (inc) {
                    mx0 = fmaxf(mx0, (ptt == 0) ? a2[0][0][r] : a2[1][0][r]);
                    mx1 = fmaxf(mx1, (ptt == 0) ? a2[0][1][r] : a2[1][1][r]);
                }
            }
        }
        mx0 += bv0;
        mx1 += bv1;
    } else {
        unsigned wm0 = vb32[wave * 2];
        unsigned wm1 = vb32[wave * 2 + 1];
#pragma unroll
        for (int ptt = 0; ptt < 2; ptt++) {
            unsigned wm = (ptt == 0) ? wm0 : wm1;
#pragma unroll
            for (int r = 0; r < 16; r++) {
                int idx = (r & 3) + 8 * (r >> 2) + 4 * g;
                bool inc = !(wave == 1 && ptt == 1) || (idx < 4);
                if (inc) {
                    bool vbit = (wm >> idx) & 1;
                    float a0 = (ptt == 0) ? a2[0][0][r] : a2[1][0][r];
                    float a1 = (ptt == 0) ? a2[0][1][r] : a2[1][1][r];
                    mx0 = fmaxf(mx0, vbit ? (a0 + bv0) : 0.0f);
                    mx1 = fmaxf(mx1, vbit ? (a1 + bv1) : 0.0f);
                }
            }
        }
    }
    mx0 = fmaxf(mx0, __shfl_xor(mx0, 32, 64));
    mx1 = fmaxf(mx1, __shfl_xor(mx1, 32, 64));
    if (lane < 32) { red[wave][mr] = mx0; red[wave][32 + mr] = mx1; }
    __syncthreads();
    if (n < F) {
        float v = fmaxf(red[0][n], red[1][n]);
        int ix = idxs[bp * 2], iy = idxs[bp * 2 + 1];
        int b = bp / P, p = bp % P;
        int cell = (b * NX + ix) * NY + iy;
        if (winner[cell] == p)
            img[(size_t)cell * F + n] = __float2bfloat16(v);
    }
}

// ---------------------------------------------------------------------------
// Scatter winner: numpy last-write-wins via atomicMax(p). Runs BEFORE pn.
// ---------------------------------------------------------------------------
__global__ __launch_bounds__(256) void winner_kernel(
    const int* __restrict__ idxs, int* __restrict__ winner)
{
    int i = blockIdx.x * 256 + threadIdx.x;
    if (i >= B * P) return;
    int ix = idxs[i * 2], iy = idxs[i * 2 + 1];
    int b = i / P, p = i % P;
    atomicMax(&winner[(b * NX + ix) * NY + iy], p);
}

// ---------------------------------------------------------------------------
// Weight converts. Conv weights -> [tap][ci/16][128 co][16 ci] bf16.
// ---------------------------------------------------------------------------
__global__ __launch_bounds__(256) void cvt_w_kernel(
    const float* __restrict__ w, __hip_bfloat16* __restrict__ wt, int cin)
{
    int idx = blockIdx.x * 256 + threadIdx.x;
    int total = 9 * cin * 128;
    if (idx >= total) return;
    int co = idx % 128;
    int rest = idx / 128;
    int ci = rest % cin;
    int t  = rest / cin;
    int c0 = ci >> 4, c16 = ci & 15;
    wt[(((size_t)(t * (cin >> 4) + c0)) * 128 + co) * 16 + c16] = __float2bfloat16(w[idx]);
}

// w1 [64 k][64 n] fp32 -> w1t [n][kk'] bf16 with k-permutation
// kk' = c0*16+g*8+j  ->  k = 16*c0 + 4*g + (j&3) + 8*(j>>2)
__global__ __launch_bounds__(256) void cvt_w1_kernel(
    const float* __restrict__ w1, __hip_bfloat16* __restrict__ w1t)
{
    int idx = blockIdx.x * 256 + threadIdx.x;
    if (idx >= F * F) return;
    int nn = idx >> 6, kk = idx & 63;
    int c0 = kk >> 4, g = (kk >> 3) & 1, j = kk & 7;
    int k = 16 * c0 + 4 * g + (j & 3) + 8 * (j >> 2);
    w1t[nn * F + kk] = __float2bfloat16(w1[k * F + nn]);
}

// w0 [8,64] fp32 + b0 [64] -> w0p [4 slots][64 feat][8 j] bf16 bits.
// slots 0,1 = w_hi; slot 2 = w_lo; slot 3 = bias (j=0: hi, j=1: lo).
__global__ __launch_bounds__(256) void cvt_w0p_kernel(
    const float* __restrict__ w0, const float* __restrict__ b0,
    short* __restrict__ w0p)
{
    int idx = blockIdx.x * 256 + threadIdx.x;
    if (idx >= 4 * 64 * 8) return;
    int j = idx & 7;
    int nn = (idx >> 3) & 63;
    int s = idx >> 9;
    short out = 0;
    if (s < 3) {
        float wv = w0[j * F + nn];
        __hip_bfloat16 hb = __float2bfloat16(wv);
        if (s < 2)      out = (short)__bfloat16_as_ushort(hb);
        else            out = bf16_bits(wv - __bfloat162float(hb));
    } else {
        float bv = b0[nn];
        __hip_bfloat16 hb = __float2bfloat16(bv);
        if (j == 0)      out = (short)__bfloat16_as_ushort(hb);
        else if (j == 1) out = bf16_bits(bv - __bfloat162float(hb));
    }
    w0p[idx] = out;
}

// ---------------------------------------------------------------------------
// MFMA implicit-GEMM 3x3 conv, SAME, Cout=128.
// R20: R16/R17 staged structure, NO setprio (R19: -38us), pass width
// halved to 16-ci. LDS double-buffer 51.2 -> 25.6 KB => 4 blocks/CU fit
// (32-wave cap binds); grid = 960 blocks ~= 3.75/CU -> effectively the
// whole grid co-resident, zero tail, max cross-block pipe interleave
// (the only lever that has ever moved this kernel: R13/R16 occupancy).
// NOT R15's failure: launch_bounds stays (512,2) = 128-reg budget (proven
// no-spill at VGPR 64-68); R15 died from (256,6)'s 85-reg spill.
// Staging: 12 chunks/pass (6 x-rows x 2 ci-granules), waves 0-3 do 2,
// waves 4-7 do 1. K-loop per tap: 2 weight loads + 2 ds_reads + 4 MFMA,
// cc = g (one 16-ci slab per pass).
// ---------------------------------------------------------------------------
template<int CIN, bool FUSE>
__global__ __launch_bounds__(512, 2) void conv_mfma(
    const __hip_bfloat16* __restrict__ in,    // [B,240,240,CIN] bf16
    const __hip_bfloat16* __restrict__ wt,    // [9][CIN/16][128][16] bf16
    const float* __restrict__ bias,           // [128]
    const float* __restrict__ w2,             // [128] (FUSE)
    const float* __restrict__ b2,             // [1]   (FUSE)
    const __hip_bfloat16* __restrict__ zerobuf, // >=16B of zeros
    __hip_bfloat16* __restrict__ out_bf,
    float* __restrict__ out_f)
{
    constexpr int NPASS = CIN / 16;       // 16 ci per pass
    constexpr int CSTR  = 400;            // column stride in granules (6*64+16)
    __shared__ short sP[2][2 * CSTR * 8]; // 2 x 12,800 B = 25,600 B
    __shared__ float sred[FUSE ? 2 : 1][4][64];

    int tid  = threadIdx.x;
    int wave = tid >> 6;       // 0..7
    int lane = tid & 63;
    int mr = lane & 31;
    int g  = lane >> 5;
    int coh = wave & 1;        // cout half
    int xr  = wave >> 1;       // output x-row within quad (0..3)
    int x0 = blockIdx.x * 4;
    int y0 = blockIdx.y * 62;  // 0,62,124,186->178 (overlap benign)
    if (y0 > 178) y0 = 178;
    int b  = blockIdx.z;
    int n0 = coh * 64;

    const short* wts = (const short*)wt;

    // stage 16-ci pass pp into dst: 12 (cc,dx) chunks of 1KB
    auto stage = [&](int pp, short* dst) {
        int gy = y0 - 1 + lane;              // dy = lane, 0..63
        bool yok = (gy >= 0 && gy < NY);
#pragma unroll
        for (int j = 0; j < 2; j++) {
            int q = j * 8 + wave;            // 0..15
            if (q < 12) {
                int cc = (q >= 6) ? 1 : 0;   // ci granule 0..1
                int dx = q - 6 * cc;         // staged x-row 0..5
                int gx = x0 - 1 + dx;
                const __hip_bfloat16* src =
                    (yok && gx >= 0 && gx < NX)
                    ? &in[(((size_t)b * NX + gx) * NY + gy) * CIN + pp * 16 + cc * 8]
                    : zerobuf;
                async_load16(src, (void*)(dst + (cc * CSTR + dx * 64) * 8));
            }
        }
    };

    f32x16 acc[2][2];
#pragma unroll
    for (int mt = 0; mt < 2; mt++)
#pragma unroll
        for (int nt = 0; nt < 2; nt++)
            acc[mt][nt] = (f32x16){0,0,0,0,0,0,0,0,0,0,0,0,0,0,0,0};

    stage(0, sP[0]);

#pragma unroll
    for (int p = 0; p < NPASS; p++) {
        __syncthreads();     // drains own vmcnt: pass p's staging landed
        if (p + 1 < NPASS)
            stage(p + 1, sP[(p + 1) & 1]);   // in flight during compute(p)
        const short* sPb = sP[p & 1];

        // ---- K-loop: 9 taps, one 16-ci slab, weights streamed from L2
#pragma unroll
        for (int tap = 0; tap < 9; tap++) {
            int kh = tap / 3, kw = tap % 3;
            int rowcol = (xr + kh) * 64 + kw;
            const short* wrow = wts + ((size_t)(tap * (CIN / 16) + p) * 128 + n0 + mr) * 16 + g * 8;
            short8 w0f = *(const short8*)(wrow);
            short8 w1f = *(const short8*)(wrow + 512);
            const short* abase = sPb + (g * CSTR + rowcol + mr) * 8;
            short8 a0 = *(const short8*)(abase);
            short8 a1 = *(const short8*)(abase + 32 * 8);   // +32 rows
            acc[0][0] = __builtin_amdgcn_mfma_f32_32x32x16_bf16(a0, w0f, acc[0][0], 0, 0, 0);
            acc[0][1] = __builtin_amdgcn_mfma_f32_32x32x16_bf16(a0, w1f, acc[0][1], 0, 0, 0);
            acc[1][0] = __builtin_amdgcn_mfma_f32_32x32x16_bf16(a1, w0f, acc[1][0], 0, 0, 0);
            acc[1][1] = __builtin_amdgcn_mfma_f32_32x32x16_bf16(a1, w1f, acc[1][1], 0, 0, 0);
        }
    }

    // ---- epilogue (C-rows >= 62 are junk: masked) ----
    float bv0 = bias[n0 + mr];
    float bv1 = bias[n0 + 32 + mr];
    if (!FUSE) {
        size_t base = ((size_t)b * NX + (x0 + xr)) * NY;
#pragma unroll
        for (int mt = 0; mt < 2; mt++) {
#pragma unroll
            for (int r = 0; r < 16; r++) {
                int row = mt * 32 + (r & 3) + 8 * (r >> 2) + 4 * g;
                if (row < 62) {
                    int y = y0 + row;
                    out_bf[(base + y) * C1 + n0 + mr]      = __float2bfloat16(tanh_fast(acc[mt][0][r] + bv0));
                    out_bf[(base + y) * C1 + n0 + 32 + mr] = __float2bfloat16(tanh_fast(acc[mt][1][r] + bv1));
                }
            }
        }
    } else {
        float w20 = w2[n0 + mr];
        float w21 = w2[n0 + 32 + mr];
#pragma unroll
        for (int mt = 0; mt < 2; mt++) {
#pragma unroll
            for (int r = 0; r < 16; r++) {
                float v = tanh_fast(acc[mt][0][r] + bv0) * w20
                        + tanh_fast(acc[mt][1][r] + bv1) * w21;
                v += __shfl_xor(v, 1, 64);
                v += __shfl_xor(v, 2, 64);
                v += __shfl_xor(v, 4, 64);
                v += __shfl_xor(v, 8, 64);
                v += __shfl_xor(v, 16, 64);
                if (mr == 0)
                    sred[coh][xr][mt * 32 + (r & 3) + 8 * (r >> 2) + 4 * g] = v;
            }
        }
        __syncthreads();
        if (tid < 256) {
            int xr2 = tid >> 6;   // 0..3
            int yy  = tid & 63;
            if (yy < 62) {
                float r = sred[0][xr2][yy] + sred[1][xr2][yy] + b2[0];
                out_f[((size_t)b * NX + (x0 + xr2)) * NY + (y0 + yy)] = fmaxf(r, 0.f);
            }
        }
    }
}

// ---------------------------------------------------------------------------
extern "C" void kernel_launch(void* const* d_in, const int* in_sizes, int n_in,
                              void* d_out, int out_size, void* d_ws, size_t ws_size,
                              hipStream_t stream) {
    const float* pillars = (const float*)d_in[0];
    const int*   idxs    = (const int*)d_in[1];
    const float* pn_w0   = (const float*)d_in[4];
    const float* pn_b0   = (const float*)d_in[5];
    const float* pn_w1   = (const float*)d_in[6];
    const float* pn_b1   = (const float*)d_in[7];
    const float* cw0     = (const float*)d_in[8];
    const float* cb0     = (const float*)d_in[9];
    const float* cw1     = (const float*)d_in[10];
    const float* cb1     = (const float*)d_in[11];
    const float* cw2     = (const float*)d_in[12];
    const float* cb2     = (const float*)d_in[13];
    float* out = (float*)d_out;

    // workspace layout
    char* ws = (char*)d_ws;
    const size_t IMG_BYTES  = (size_t)B * NX * NY * F * 2;
    const size_t OUT1_BYTES = (size_t)B * NX * NY * C1 * 2;
    const size_t WIN_BYTES  = (size_t)B * NX * NY * 4;
    const size_t PMAX_BYTES = (size_t)B * P * F * 4;   // (unused since R17)
    const size_t WT1_BYTES  = (size_t)9 * C1 * F * 2;
    const size_t WT2_BYTES  = (size_t)9 * C1 * C1 * 2;
    const size_t W1T_BYTES  = (size_t)F * F * 2;
    const size_t W0P_BYTES  = (size_t)4 * 64 * 8 * 2;
    __hip_bfloat16* img  = (__hip_bfloat16*)ws;
    __hip_bfloat16* out1 = (__hip_bfloat16*)(ws + IMG_BYTES);
    int*   winner = (int*)(ws + IMG_BYTES + OUT1_BYTES);
    __hip_bfloat16* wt1 = (__hip_bfloat16*)(ws + IMG_BYTES + OUT1_BYTES + WIN_BYTES + PMAX_BYTES);
    __hip_bfloat16* wt2 = (__hip_bfloat16*)(ws + IMG_BYTES + OUT1_BYTES + WIN_BYTES + PMAX_BYTES + WT1_BYTES);
    __hip_bfloat16* w1t = (__hip_bfloat16*)(ws + IMG_BYTES + OUT1_BYTES + WIN_BYTES + PMAX_BYTES + WT1_BYTES + WT2_BYTES);
    short* w0p = (short*)(ws + IMG_BYTES + OUT1_BYTES + WIN_BYTES + PMAX_BYTES + WT1_BYTES + WT2_BYTES + W1T_BYTES);
    __hip_bfloat16* zerobuf = (__hip_bfloat16*)(ws + IMG_BYTES + OUT1_BYTES + WIN_BYTES + PMAX_BYTES + WT1_BYTES + WT2_BYTES + W1T_BYTES + W0P_BYTES);

    hipMemsetAsync(img, 0, IMG_BYTES, stream);
    hipMemsetAsync(winner, 0xFF, WIN_BYTES, stream);   // -1
    hipMemsetAsync(zerobuf, 0, 64, stream);            // OOB target for async staging

    cvt_w_kernel<<<(9 * F * C1 + 255) / 256, 256, 0, stream>>>(cw0, wt1, F);
    cvt_w_kernel<<<(9 * C1 * C1 + 255) / 256, 256, 0, stream>>>(cw1, wt2, C1);
    cvt_w1_kernel<<<(F * F + 255) / 256, 256, 0, stream>>>(pn_w1, w1t);
    cvt_w0p_kernel<<<(4 * 64 * 8 + 255) / 256, 256, 0, stream>>>(pn_w0, pn_b0, w0p);

    winner_kernel<<<(B * P + 255) / 256, 256, 0, stream>>>(idxs, winner);
    pn_mfma_kernel<<<B * P, 128, 0, stream>>>(pillars, w0p, w1t, pn_b1,
                                              idxs, winner, img);

    conv_mfma<F, false><<<dim3(NX / 4, 4, B), 512, 0, stream>>>(
        img, wt1, cb0, nullptr, nullptr, zerobuf, out1, nullptr);
    conv_mfma<C1, true><<<dim3(NX / 4, 4, B), 512, 0, stream>>>(
        out1, wt2, cb1, cw2, cb2, zerobuf, nullptr, out);
}